// Round 23
// baseline (327.626 us; speedup 1.0000x reference)
//
#include <hip/hip_runtime.h>
#include <hip/hip_bf16.h>
#include <cmath>

#define NN 20000   // nodes
#define NE 60000   // edges
#define NS 3000    // subgraphs
#define NG 128     // graphs
#define HIDN 128   // hidden dim of edge-attr MLP
#define SCB 79     // scan blocks = ceil(NN/256)
#define TILES 938  // ceil(NE/64)
#define SLST 3840000   // slice stride in f16 elems = NE*64

typedef float f32x16 __attribute__((ext_vector_type(16)));
typedef _Float16 f16x8 __attribute__((ext_vector_type(8)));

__device__ __forceinline__ float eluf(float v) { return v > 0.f ? v : expm1f(v); }

// async global->LDS, 16B per lane; lds ptr must be wave-uniform (HW writes base + lane*16)
__device__ __forceinline__ void gload_lds16(const void* g, void* l) {
    __builtin_amdgcn_global_load_lds(
        (const __attribute__((address_space(1))) unsigned int*)g,
        (__attribute__((address_space(3))) unsigned int*)l, 16, 0, 0);
}

__device__ __forceinline__ void vmwait0() {
    asm volatile("s_waitcnt vmcnt(0)" ::: "memory");
}
__device__ __forceinline__ void vmwait8() {
    asm volatile("s_waitcnt vmcnt(8)" ::: "memory");
}

// ================= one-time edge sort by dst (counting sort) =================
__global__ void k_hist(const int* __restrict__ dst, int* __restrict__ deg) {
    int e = blockIdx.x * 256 + threadIdx.x;
    if (e < NE) atomicAdd(&deg[dst[e]], 1);
}

__global__ void k_scan1(const int* __restrict__ deg, int* __restrict__ bsum) {
    __shared__ int s[256];
    const int t = threadIdx.x;
    int i = blockIdx.x * 256 + t;
    s[t] = (i < NN) ? deg[i] : 0;
    __syncthreads();
#pragma unroll
    for (int off = 128; off > 0; off >>= 1) {
        if (t < off) s[t] += s[t + off];
        __syncthreads();
    }
    if (t == 0) bsum[blockIdx.x] = s[0];
}

__global__ void k_scan2(const int* __restrict__ bsum, int* __restrict__ boff) {
    __shared__ int s[SCB];
    const int t = threadIdx.x;
    if (t < SCB) s[t] = bsum[t];
    __syncthreads();
    if (t == 0) {
        int acc = 0;
        for (int i = 0; i < SCB; ++i) { int v = s[i]; s[i] = acc; acc += v; }
    }
    __syncthreads();
    if (t < SCB) boff[t] = s[t];
}

__global__ void k_scan3(const int* __restrict__ deg, const int* __restrict__ boff,
                        int* __restrict__ rowptr) {
    __shared__ int s[256];
    const int t = threadIdx.x;
    int i = blockIdx.x * 256 + t;
    int v = (i < NN) ? deg[i] : 0;
    s[t] = v;
    __syncthreads();
#pragma unroll
    for (int off = 1; off < 256; off <<= 1) {
        int a = (t >= off) ? s[t - off] : 0;
        __syncthreads();
        s[t] += a;
        __syncthreads();
    }
    if (i < NN) rowptr[i + 1] = boff[blockIdx.x] + s[t];
    if (i == 0) rowptr[0] = 0;
}

__global__ void k_scatter(const int* __restrict__ src, const int* __restrict__ dst,
                          const int* __restrict__ rowptr, int* __restrict__ tmp,
                          int* __restrict__ eord, int* __restrict__ srcS) {
    int e = blockIdx.x * 256 + threadIdx.x;
    if (e >= NE) return;
    int d = dst[e];
    int pos = rowptr[d] + atomicAdd(&tmp[d], 1);
    eord[pos] = e;
    srcS[pos] = src[e];
}

// ---------------- combined prep: 3x w2t transposes + x16h, one dispatch ----------------
#define PRE_N0 66048    // 32*129*16   (layer 0)
#define PRE_N1 264192   // 64*129*32   (layer 1)
#define PRE_N2 528384   // 64*129*64   (layer 2)
#define PRE_N3 320000   // NN*16       (x16h)
#define PRE_TOT (PRE_N0 + PRE_N1 + PRE_N2 + PRE_N3)

__global__ void k_prep(const float* __restrict__ w20, const float* __restrict__ b20,
                       const float* __restrict__ w21, const float* __restrict__ b21,
                       const float* __restrict__ w22, const float* __restrict__ b22,
                       const float* __restrict__ x,
                       _Float16* __restrict__ w2t0, _Float16* __restrict__ w2t1,
                       _Float16* __restrict__ w2t2, _Float16* __restrict__ x16h) {
    int idx = blockIdx.x * 256 + threadIdx.x;
    if (idx < PRE_N0) {
        constexpr int KP = 129 * 16, KF = 128 * 16, MO = 32;
        int o = idx / KP, kg = idx % KP;
        float v = (kg < KF) ? w20[(size_t)kg * MO + o] : b20[(kg - KF) * MO + o];
        w2t0[idx] = (_Float16)v;
    } else if (idx < PRE_N0 + PRE_N1) {
        int i2 = idx - PRE_N0;
        constexpr int KP = 129 * 32, KF = 128 * 32, MO = 64;
        int o = i2 / KP, kg = i2 % KP;
        float v = (kg < KF) ? w21[(size_t)kg * MO + o] : b21[(kg - KF) * MO + o];
        w2t1[i2] = (_Float16)v;
    } else if (idx < PRE_N0 + PRE_N1 + PRE_N2) {
        int i2 = idx - PRE_N0 - PRE_N1;
        constexpr int KP = 129 * 64, KF = 128 * 64, MO = 64;
        int o = i2 / KP, kg = i2 % KP;
        float v = (kg < KF) ? w22[(size_t)kg * MO + o] : b22[(kg - KF) * MO + o];
        w2t2[i2] = (_Float16)v;
    } else if (idx < PRE_TOT) {
        int i2 = idx - PRE_N0 - PRE_N1 - PRE_N2;
        int n = i2 >> 4, i = i2 & 15;
        x16h[i2] = (_Float16)x[n * 24 + i];
    }
}

// ---------------- streaming MFMA edge kernel (fallback path only) ----------
template <int MI, int MO, int XS>
__global__ __launch_bounds__(256, 2) void k_edgeB(
    const _Float16* __restrict__ xi, const float* __restrict__ ea,
    const float* __restrict__ w1, const float* __restrict__ b1,
    const _Float16* __restrict__ w2t, const int* __restrict__ srcS,
    const int* __restrict__ eord, _Float16* __restrict__ msg) {
    constexpr int PH  = MI / 16;
    constexpr int KP  = 129 * MI;
    constexpr int NT  = MO / 32;
    constexpr int CH  = 16 / (PH * NT);
    constexpr int NCH = 64 / CH;
    static_assert(CH * PH * NT == 16, "ITEMS must be 16");

    __shared__ __align__(16) _Float16 sb[2][2][16 * 512];

    const int lane = threadIdx.x & 63;
    const int w    = threadIdx.x >> 6;
    const int mg   = w & 1;
    const int kh   = w >> 1;
    const int lo5  = lane & 31;
    const int hi   = lane >> 5;
    const int e0   = blockIdx.x * 128 + mg * 64;
    const int kb   = kh * 64;

    const int rc0 = min(e0 + lo5, NE - 1);
    const int rc1 = min(e0 + 32 + lo5, NE - 1);
    const int s0 = srcS[rc0];
    const int s1 = srcS[rc1];

    float ea0[5], ea1[5];
    {
        const int eo0 = eord[rc0], eo1 = eord[rc1];
#pragma unroll
        for (int d = 0; d < 5; ++d) {
            ea0[d] = ea[eo0 * 5 + d];
            ea1[d] = ea[eo1 * 5 + d];
        }
    }

    f16x8 xr0[PH], xr1[PH];
    {
        const _Float16* xb0 = xi + (size_t)s0 * XS + hi * 8;
        const _Float16* xb1 = xi + (size_t)s1 * XS + hi * 8;
#pragma unroll
        for (int p = 0; p < PH; ++p) {
            xr0[p] = *reinterpret_cast<const f16x8*>(xb0 + p * 16);
            xr1[p] = *reinterpret_cast<const f16x8*>(xb1 + p * 16);
        }
    }

    f32x16 acc[2][NT];
#pragma unroll
    for (int m = 0; m < 2; ++m)
#pragma unroll
        for (int n = 0; n < NT; ++n)
#pragma unroll
            for (int i = 0; i < 16; ++i) acc[m][n][i] = 0.f;

    auto stage = [&](int buf, int kc) {
#pragma unroll
        for (int jj = 0; jj < 8; ++jj) {
            const int j  = mg + jj * 2;
            const int n  = j % NT;
            const int kp = j / NT;
            const int p  = kp % PH;
            const int kk = kp / PH;
            gload_lds16(w2t + (size_t)(n * 32 + lo5) * KP
                            + (size_t)(kb + kc + kk) * MI + p * 16 + hi * 8,
                        &sb[kh][buf][j * 512]);
        }
    };

    auto calc_h = [&](int kc, _Float16* h0, _Float16* h1) {
#pragma unroll
        for (int kk = 0; kk < CH; ++kk) {
            const int k = kb + kc + kk;
            const float c0 = w1[0 * HIDN + k], c1 = w1[1 * HIDN + k],
                        c2 = w1[2 * HIDN + k], c3 = w1[3 * HIDN + k],
                        c4 = w1[4 * HIDN + k], bb = b1[k];
            float t0 = bb, t1 = bb;
            t0 = fmaf(ea0[0], c0, t0); t1 = fmaf(ea1[0], c0, t1);
            t0 = fmaf(ea0[1], c1, t0); t1 = fmaf(ea1[1], c1, t1);
            t0 = fmaf(ea0[2], c2, t0); t1 = fmaf(ea1[2], c2, t1);
            t0 = fmaf(ea0[3], c3, t0); t1 = fmaf(ea1[3], c3, t1);
            t0 = fmaf(ea0[4], c4, t0); t1 = fmaf(ea1[4], c4, t1);
            h0[kk] = (_Float16)fmaxf(t0, 0.f);
            h1[kk] = (_Float16)fmaxf(t1, 0.f);
        }
    };

    auto compute = [&](int buf, const _Float16* h0, const _Float16* h1) {
        const _Float16* sbc = &sb[kh][buf][0];
#pragma unroll
        for (int kk = 0; kk < CH; ++kk) {
            const _Float16 hv0 = h0[kk];
            const _Float16 hv1 = h1[kk];
            const f16x8 h80 = {hv0, hv0, hv0, hv0, hv0, hv0, hv0, hv0};
            const f16x8 h81 = {hv1, hv1, hv1, hv1, hv1, hv1, hv1, hv1};
#pragma unroll
            for (int p = 0; p < PH; ++p) {
                const f16x8 af0 = xr0[p] * h80;
                const f16x8 af1 = xr1[p] * h81;
#pragma unroll
                for (int n = 0; n < NT; ++n) {
                    const f16x8 bv = *reinterpret_cast<const f16x8*>(
                        &sbc[((kk * PH + p) * NT + n) * 512 + lane * 8]);
                    acc[0][n] = __builtin_amdgcn_mfma_f32_32x32x16_f16(af0, bv, acc[0][n], 0, 0, 0);
                    acc[1][n] = __builtin_amdgcn_mfma_f32_32x32x16_f16(af1, bv, acc[1][n], 0, 0, 0);
                }
            }
        }
    };

    _Float16 hA0[CH], hA1[CH], hB0[CH], hB1[CH];

    stage(0, 0);
    calc_h(0, hA0, hA1);

    for (int c = 0; c < NCH; c += 2) {
        stage(1, (c + 1) * CH);
        calc_h((c + 1) * CH, hB0, hB1);
        vmwait8();
        __builtin_amdgcn_sched_barrier(0);
        __builtin_amdgcn_s_barrier();
        __builtin_amdgcn_sched_barrier(0);
        compute(0, hA0, hA1);
        __builtin_amdgcn_sched_barrier(0);
        __builtin_amdgcn_s_barrier();

        const bool pf = (c + 2 < NCH);
        if (pf) {
            stage(0, (c + 2) * CH);
            calc_h((c + 2) * CH, hA0, hA1);
            vmwait8();
        } else {
            vmwait0();
        }
        __builtin_amdgcn_sched_barrier(0);
        __builtin_amdgcn_s_barrier();
        __builtin_amdgcn_sched_barrier(0);
        compute(1, hB0, hB1);
        __builtin_amdgcn_sched_barrier(0);
        __builtin_amdgcn_s_barrier();
    }

    if (kh == 1) {
#pragma unroll
        for (int p = 0; p < PH; ++p) {
#pragma unroll
            for (int n = 0; n < NT; ++n) {
                const f16x8 bv = *reinterpret_cast<const f16x8*>(
                    w2t + (size_t)(n * 32 + lo5) * KP + (size_t)128 * MI + p * 16 + hi * 8);
                acc[0][n] = __builtin_amdgcn_mfma_f32_32x32x16_f16(xr0[p], bv, acc[0][n], 0, 0, 0);
                acc[1][n] = __builtin_amdgcn_mfma_f32_32x32x16_f16(xr1[p], bv, acc[1][n], 0, 0, 0);
            }
        }
    }

    __syncthreads();
    float* red = reinterpret_cast<float*>(&sb[0][0][0]);
    if (kh == 1) {
#pragma unroll
        for (int m = 0; m < 2; ++m)
#pragma unroll
            for (int n = 0; n < NT; ++n) {
                float* d = red + (size_t)((mg * 2 + m) * NT + n) * 1024 + lane;
#pragma unroll
                for (int i = 0; i < 16; ++i) d[i * 64] = acc[m][n][i];
            }
    }
    __syncthreads();
    if (kh == 0) {
#pragma unroll
        for (int m = 0; m < 2; ++m)
#pragma unroll
            for (int n = 0; n < NT; ++n) {
                const float* s = red + (size_t)((mg * 2 + m) * NT + n) * 1024 + lane;
#pragma unroll
                for (int i = 0; i < 16; ++i) acc[m][n][i] += s[i * 64];
            }
#pragma unroll
        for (int m = 0; m < 2; ++m)
#pragma unroll
            for (int q = 0; q < 4; ++q)
#pragma unroll
                for (int a2 = 0; a2 < 4; ++a2) {
                    const int e = e0 + m * 32 + 4 * hi + 8 * q + a2;
                    if (e < NE) {
#pragma unroll
                        for (int n = 0; n < NT; ++n)
                            msg[(size_t)e * MO + n * 32 + lo5] =
                                (_Float16)acc[m][n][4 * q + a2];
                    }
                }
    }
}

// ---------------- persistent-B MFMA edge kernel (k-slice decomposition, full MO) ----------
// blockIdx.y = k-slice (NSL slices of KSL k, last has 129-(NSL-1)*KSL incl. b2-tail).
// B-slice loaded ONCE into LDS; WV waves free-run over 64-edge tiles, zero barriers.
// Slice sl writes partial msgP + sl*SLST; partials summed by k_red (NSL>1).
template <int MI, int MO, int XS, int KSL, int NSL, int WV>
__global__ __launch_bounds__(WV * 64, WV / 4) void k_edgeP(
    const _Float16* __restrict__ xi, const float* __restrict__ ea,
    const float* __restrict__ w1, const float* __restrict__ b1,
    const _Float16* __restrict__ w2t, const int* __restrict__ srcS,
    const int* __restrict__ eord, _Float16* __restrict__ msgP, int tilesPerBlock) {
    constexpr int PH = MI / 16;
    constexpr int KP = 129 * MI;
    constexpr int NT = MO / 32;
    constexpr int LASTK = 129 - (NSL - 1) * KSL;
    constexpr int MAXITEMS = LASTK * PH * NT;   // last slice is largest

    __shared__ __align__(16) _Float16 sb[MAXITEMS * 512];

    const int t    = threadIdx.x;
    const int lane = t & 63;
    const int w    = t >> 6;
    const int lo5  = lane & 31;
    const int hi   = lane >> 5;

    const int sl    = blockIdx.y;
    const int k0    = sl * KSL;
    const int kspan = (sl == NSL - 1) ? LASTK : KSL;
    const int items = kspan * PH * NT;

    // one-time B-slice load
    for (int j = w; j < items; j += WV) {
        const int kk  = j / (PH * NT);
        const int rem = j % (PH * NT);
        const int p   = rem / NT;
        const int n   = rem % NT;
        gload_lds16(w2t + (size_t)(n * 32 + lo5) * KP
                        + (size_t)(k0 + kk) * MI + p * 16 + hi * 8,
                    &sb[j * 512]);
    }
    vmwait0();
    __syncthreads();

    _Float16* msgS = msgP + (size_t)sl * SLST;
    const int tile0 = blockIdx.x * tilesPerBlock;
    const int tile1 = min(tile0 + tilesPerBlock, TILES);

    for (int tile = tile0 + w; tile < tile1; tile += WV) {
        const int e0  = tile * 64;
        const int rc0 = min(e0 + lo5, NE - 1);
        const int rc1 = min(e0 + 32 + lo5, NE - 1);
        const int s0 = srcS[rc0];
        const int s1 = srcS[rc1];

        float ea0[5], ea1[5];
        {
            const int eo0 = eord[rc0], eo1 = eord[rc1];
#pragma unroll
            for (int d = 0; d < 5; ++d) {
                ea0[d] = ea[eo0 * 5 + d];
                ea1[d] = ea[eo1 * 5 + d];
            }
        }

        f16x8 xr0[PH], xr1[PH];
        {
            const _Float16* xb0 = xi + (size_t)s0 * XS + hi * 8;
            const _Float16* xb1 = xi + (size_t)s1 * XS + hi * 8;
#pragma unroll
            for (int p = 0; p < PH; ++p) {
                xr0[p] = *reinterpret_cast<const f16x8*>(xb0 + p * 16);
                xr1[p] = *reinterpret_cast<const f16x8*>(xb1 + p * 16);
            }
        }

        f32x16 acc[2][NT];
#pragma unroll
        for (int m = 0; m < 2; ++m)
#pragma unroll
            for (int n = 0; n < NT; ++n)
#pragma unroll
                for (int i = 0; i < 16; ++i) acc[m][n][i] = 0.f;

        for (int kk2 = 0; kk2 < kspan; ++kk2) {
            const int k = k0 + kk2;
            _Float16 hv0, hv1;
            if (k < 128) {
                const float c0 = w1[0 * HIDN + k], c1 = w1[1 * HIDN + k],
                            c2 = w1[2 * HIDN + k], c3 = w1[3 * HIDN + k],
                            c4 = w1[4 * HIDN + k], bb = b1[k];
                float t0 = bb, t1 = bb;
                t0 = fmaf(ea0[0], c0, t0); t1 = fmaf(ea1[0], c0, t1);
                t0 = fmaf(ea0[1], c1, t0); t1 = fmaf(ea1[1], c1, t1);
                t0 = fmaf(ea0[2], c2, t0); t1 = fmaf(ea1[2], c2, t1);
                t0 = fmaf(ea0[3], c3, t0); t1 = fmaf(ea1[3], c3, t1);
                t0 = fmaf(ea0[4], c4, t0); t1 = fmaf(ea1[4], c4, t1);
                hv0 = (_Float16)fmaxf(t0, 0.f);
                hv1 = (_Float16)fmaxf(t1, 0.f);
            } else {
                hv0 = (_Float16)1.0f;
                hv1 = (_Float16)1.0f;
            }
            const f16x8 h80 = {hv0, hv0, hv0, hv0, hv0, hv0, hv0, hv0};
            const f16x8 h81 = {hv1, hv1, hv1, hv1, hv1, hv1, hv1, hv1};
#pragma unroll
            for (int p = 0; p < PH; ++p) {
                const f16x8 af0 = xr0[p] * h80;
                const f16x8 af1 = xr1[p] * h81;
#pragma unroll
                for (int n = 0; n < NT; ++n) {
                    const f16x8 bv = *reinterpret_cast<const f16x8*>(
                        &sb[((kk2 * PH + p) * NT + n) * 512 + lane * 8]);
                    acc[0][n] = __builtin_amdgcn_mfma_f32_32x32x16_f16(af0, bv, acc[0][n], 0, 0, 0);
                    acc[1][n] = __builtin_amdgcn_mfma_f32_32x32x16_f16(af1, bv, acc[1][n], 0, 0, 0);
                }
            }
        }

        // store partial: C layout col = lane&31, row = (reg&3) + 8*(reg>>2) + 4*(lane>>5)
#pragma unroll
        for (int m = 0; m < 2; ++m)
#pragma unroll
            for (int q = 0; q < 4; ++q)
#pragma unroll
                for (int a2 = 0; a2 < 4; ++a2) {
                    const int e = e0 + m * 32 + 4 * hi + 8 * q + a2;
                    if (e < NE) {
#pragma unroll
                        for (int n = 0; n < NT; ++n)
                            msgS[(size_t)e * MO + n * 32 + lo5] =
                                (_Float16)acc[m][n][4 * q + a2];
                    }
                }
    }
}

// ---------------- slice reduction: msg[idx] = sum over NSL partials (coalesced f16x8) ------
template <int NSL>
__global__ void k_red(_Float16* __restrict__ msgP) {
    int idx = blockIdx.x * 256 + threadIdx.x;   // f16x8 units; total = NE*64/8 = 480000
    if (idx >= NE * 8) return;
    float a[8] = {0, 0, 0, 0, 0, 0, 0, 0};
#pragma unroll
    for (int sl = 0; sl < NSL; ++sl) {
        const f16x8 v = *reinterpret_cast<const f16x8*>(msgP + (size_t)sl * SLST + (size_t)idx * 8);
#pragma unroll
        for (int i = 0; i < 8; ++i) a[i] += (float)v[i];
    }
    f16x8 r;
#pragma unroll
    for (int i = 0; i < 8; ++i) r[i] = (_Float16)a[i];
    *reinterpret_cast<f16x8*>(msgP + (size_t)idx * 8) = r;
}

// ---------------- vectorized agg (single reduced msg): out = elu(bias + xi@root + CSR-sum) --
// thread = (node, 8-col group); one f16x8 read per edge.
template <int MI, int MO, int XS>
__global__ void k_aggF(const _Float16* __restrict__ msg, const int* __restrict__ rowptr,
                       const float* __restrict__ xi, const float* __restrict__ root,
                       const float* __restrict__ bias, float* __restrict__ out,
                       _Float16* __restrict__ outh) {
    constexpr int OG = MO / 8;
    int idx = blockIdx.x * 256 + threadIdx.x;
    if (idx >= NN * OG) return;
    const int n = idx / OG, og = idx % OG, ob = og * 8;

    float a[8];
#pragma unroll
    for (int c = 0; c < 8; ++c) a[c] = bias[ob + c];

    for (int i = 0; i < MI; ++i) {
        const float xv = xi[(size_t)n * XS + i];
        const float4 r0 = *reinterpret_cast<const float4*>(&root[i * MO + ob]);
        const float4 r1 = *reinterpret_cast<const float4*>(&root[i * MO + ob + 4]);
        a[0] = fmaf(xv, r0.x, a[0]); a[1] = fmaf(xv, r0.y, a[1]);
        a[2] = fmaf(xv, r0.z, a[2]); a[3] = fmaf(xv, r0.w, a[3]);
        a[4] = fmaf(xv, r1.x, a[4]); a[5] = fmaf(xv, r1.y, a[5]);
        a[6] = fmaf(xv, r1.z, a[6]); a[7] = fmaf(xv, r1.w, a[7]);
    }

    const int j0 = rowptr[n], j1 = rowptr[n + 1];
    for (int j = j0; j < j1; ++j) {
        const f16x8 v = *reinterpret_cast<const f16x8*>(msg + (size_t)j * MO + ob);
#pragma unroll
        for (int c = 0; c < 8; ++c) a[c] += (float)v[c];
    }

    float r[8];
    f16x8 rh;
#pragma unroll
    for (int c = 0; c < 8; ++c) { r[c] = eluf(a[c]); rh[c] = (_Float16)r[c]; }
    *reinterpret_cast<float4*>(&out[(size_t)n * MO + ob]) = make_float4(r[0], r[1], r[2], r[3]);
    *reinterpret_cast<float4*>(&out[(size_t)n * MO + ob + 4]) = make_float4(r[4], r[5], r[6], r[7]);
    *reinterpret_cast<f16x8*>(&outh[(size_t)n * MO + ob]) = rh;
}

// ---------------- vectorized layer-2 agg + node->subgraph pooling (single reduced msg) -----
// thread = (node, col-group og in [0,9)); og<8 = conv outputs, og==8 = x_cont cols 64..71.
__global__ void k_agg_poolF(const _Float16* __restrict__ msg, const int* __restrict__ rowptr,
                            const float* __restrict__ xi, const float* __restrict__ root,
                            const float* __restrict__ bias, const float* __restrict__ x,
                            const int* __restrict__ n2s, float* __restrict__ xs_sum,
                            float* __restrict__ cs) {
    int idx = blockIdx.x * 256 + threadIdx.x;
    if (idx >= NN * 9) return;
    const int n = idx / 9, og = idx % 9;

    float a[8];
    if (og < 8) {
        const int ob = og * 8;
#pragma unroll
        for (int c = 0; c < 8; ++c) a[c] = bias[ob + c];
        for (int i = 0; i < 64; ++i) {
            const float xv = xi[(size_t)n * 64 + i];
            const float4 r0 = *reinterpret_cast<const float4*>(&root[i * 64 + ob]);
            const float4 r1 = *reinterpret_cast<const float4*>(&root[i * 64 + ob + 4]);
            a[0] = fmaf(xv, r0.x, a[0]); a[1] = fmaf(xv, r0.y, a[1]);
            a[2] = fmaf(xv, r0.z, a[2]); a[3] = fmaf(xv, r0.w, a[3]);
            a[4] = fmaf(xv, r1.x, a[4]); a[5] = fmaf(xv, r1.y, a[5]);
            a[6] = fmaf(xv, r1.z, a[6]); a[7] = fmaf(xv, r1.w, a[7]);
        }
        const int j0 = rowptr[n], j1 = rowptr[n + 1];
        for (int j = j0; j < j1; ++j) {
            const f16x8 v = *reinterpret_cast<const f16x8*>(msg + (size_t)j * 64 + ob);
#pragma unroll
            for (int c = 0; c < 8; ++c) a[c] += (float)v[c];
        }
#pragma unroll
        for (int c = 0; c < 8; ++c) a[c] = eluf(a[c]);
    } else {
#pragma unroll
        for (int c = 0; c < 8; ++c) a[c] = x[n * 24 + 16 + c];
    }

    const int sg = n2s[n];
    const int base = sg * 72 + og * 8;
#pragma unroll
    for (int c = 0; c < 8; ++c) atomicAdd(&xs_sum[base + c], a[c]);
    if (og == 0) atomicAdd(&cs[sg], 1.f);
}

// ---------------- pool subgraphs -> graphs (mean of means) ----------------
__global__ void k_pool_g(const float* __restrict__ xs_sum, const float* __restrict__ cs,
                         const int* __restrict__ s2g, float* __restrict__ xg_sum,
                         float* __restrict__ cg) {
    int idx = blockIdx.x * 256 + threadIdx.x;
    if (idx >= NS * 72) return;
    int s = idx / 72, j = idx % 72;
    float v = xs_sum[s * 72 + j] / fmaxf(cs[s], 1.f);
    int g = s2g[s];
    atomicAdd(&xg_sum[g * 72 + j], v);
    if (j == 0) atomicAdd(&cg[g], 1.f);
}

// ---------------- final MLP: 72 -> 36 -> 18 -> 1 ----------------
__global__ void k_fc(const float* __restrict__ xg_sum, const float* __restrict__ cg,
                     const float* __restrict__ w1, const float* __restrict__ b1,
                     const float* __restrict__ w2, const float* __restrict__ b2,
                     const float* __restrict__ w3, const float* __restrict__ b3,
                     float* __restrict__ out) {
    int g = threadIdx.x;
    if (g >= NG) return;
    float inv = 1.f / fmaxf(cg[g], 1.f);
    float v[72];
#pragma unroll
    for (int j = 0; j < 72; ++j) v[j] = xg_sum[g * 72 + j] * inv;
    float h1[36];
#pragma unroll
    for (int o = 0; o < 36; ++o) {
        float s = b1[o];
#pragma unroll
        for (int i = 0; i < 72; ++i) s = fmaf(v[i], w1[i * 36 + o], s);
        h1[o] = eluf(s);
    }
    float h2[18];
#pragma unroll
    for (int o = 0; o < 18; ++o) {
        float s = b2[o];
#pragma unroll
        for (int i = 0; i < 36; ++i) s = fmaf(h1[i], w2[i * 18 + o], s);
        h2[o] = eluf(s);
    }
    float s = b3[0];
#pragma unroll
    for (int i = 0; i < 18; ++i) s = fmaf(h2[i], w3[i], s);
    out[g] = s;
}

// ---------------- launcher ----------------
extern "C" void kernel_launch(void* const* d_in, const int* in_sizes, int n_in,
                              void* d_out, int out_size, void* d_ws, size_t ws_size,
                              hipStream_t stream) {
    const float* x   = (const float*)d_in[0];
    const int*   ei  = (const int*)d_in[1];
    const float* ea  = (const float*)d_in[2];
    const int*   n2s = (const int*)d_in[3];
    const int*   s2g = (const int*)d_in[4];
    const int* src = ei;
    const int* dst = ei + NE;

    const float* cw1[3]   = {(const float*)d_in[5],  (const float*)d_in[11], (const float*)d_in[17]};
    const float* cb1[3]   = {(const float*)d_in[6],  (const float*)d_in[12], (const float*)d_in[18]};
    const float* cw2[3]   = {(const float*)d_in[7],  (const float*)d_in[13], (const float*)d_in[19]};
    const float* cb2[3]   = {(const float*)d_in[8],  (const float*)d_in[14], (const float*)d_in[20]};
    const float* croot[3] = {(const float*)d_in[9],  (const float*)d_in[15], (const float*)d_in[21]};
    const float* cbias[3] = {(const float*)d_in[10], (const float*)d_in[16], (const float*)d_in[22]};
    const float* fc1w = (const float*)d_in[23];
    const float* fc1b = (const float*)d_in[24];
    const float* fc2w = (const float*)d_in[25];
    const float* fc2b = (const float*)d_in[26];
    const float* fc3w = (const float*)d_in[27];
    const float* fc3b = (const float*)d_in[28];

    // ---- workspace layout (bytes, 16-aligned) ----
    char* W = (char*)d_ws;
    float*    xiA   = (float*)(W);                    // NN*64*4    =  5,120,000
    float*    xiB   = (float*)(W + 5120000);          // NN*64*4    =  5,120,000
    _Float16* xiAh  = (_Float16*)(W + 10240000);      // NN*64*2    =  2,560,000
    _Float16* xiBh  = (_Float16*)(W + 12800000);      // NN*64*2    =  2,560,000
    _Float16* x16h  = (_Float16*)(W + 15360000);      // NN*16*2    =    640,000
    // zero region (single memset): xs_sum | cs | xg_sum | cg | deg | tmp
    float*    xs_sum= (float*)(W + 16000000);         // NS*72*4    =    864,000
    float*    cs    = (float*)(W + 16864000);         // NS*4       =     12,000
    float*    xg_sum= (float*)(W + 16876000);         // NG*72*4    =     36,864
    float*    cg    = (float*)(W + 16912864);         // NG*4       =        512
    int*      deg   = (int*)(W + 16913376);           // NN*4       =     80,000
    int*      tmp   = (int*)(W + 16993376);           // NN*4       =     80,000
    _Float16* w2t0  = (_Float16*)(W + 17073376);      // 32*2064*2  =    132,096
    _Float16* w2t1  = (_Float16*)(W + 17205472);      // 64*4128*2  =    528,384
    _Float16* w2t2  = (_Float16*)(W + 17733856);      // 64*8256*2  =  1,056,768
    int*      rowptr= (int*)(W + 18790624);           // (NN+1)*4   ->    80,016
    int*      eord  = (int*)(W + 18870640);           // NE*4       =    240,000
    int*      srcS  = (int*)(W + 19110640);           // NE*4       =    240,000
    int*      bsum  = (int*)(W + 19350640);           // SCB*4
    int*      boff  = (int*)(W + 19350960);           // SCB*4
    _Float16* msgP  = (_Float16*)(W + 19351296);      // up to 8 x NE*64*2 = 61,440,000
    const size_t NEED_P = 19351296ull + 8ull * 7680000ull;   // 80,791,296
    const bool useP = (ws_size >= NEED_P);
    _Float16* msg = msgP;   // slice 0 doubles as the reduced msg buffer

    // single memset: pooling accumulators + sort counters (contiguous)
    hipMemsetAsync(xs_sum, 0, 1073376, stream);

    // ---- one-time edge sort by dst (hierarchical scan) ----
    k_hist<<<(NE + 255) / 256, 256, 0, stream>>>(dst, deg);
    k_scan1<<<SCB, 256, 0, stream>>>(deg, bsum);
    k_scan2<<<1, 128, 0, stream>>>(bsum, boff);
    k_scan3<<<SCB, 256, 0, stream>>>(deg, boff, rowptr);
    k_scatter<<<(NE + 255) / 256, 256, 0, stream>>>(src, dst, rowptr, tmp, eord, srcS);

    // combined prep: w2t x3 + x16h in one dispatch
    k_prep<<<(PRE_TOT + 255) / 256, 256, 0, stream>>>(
        cw2[0], cb2[0], cw2[1], cb2[1], cw2[2], cb2[2], x, w2t0, w2t1, w2t2, x16h);

    const int EB = (NE + 127) / 128;   // 469 blocks of 4 waves (fallback)
    const int REDB = (NE * 8 + 255) / 256;  // 1875

    if (useP) {
        // ---- layer 0: persistent-B, single slice (129 KB LDS), 8-wave blocks ----
        {
            const int XB = 118, TPB = 8;   // 118*8 = 944 >= 938 tiles
            k_edgeP<16, 32, 16, 129, 1, 8><<<dim3(XB, 1), 512, 0, stream>>>(
                x16h, ea, cw1[0], cb1[0], w2t0, srcS, eord, msg, TPB);
        }
        k_aggF<16, 32, 24><<<(NN * 4 + 255) / 256, 256, 0, stream>>>(
            msg, rowptr, x, croot[0], cbias[0], xiB, xiBh);

        // ---- layer 1: persistent-B, 4 k-slices (<=132 KB LDS), 12-wave blocks ----
        {
            const int XB = 64, TPB = (TILES + 63) / 64;   // 15
            k_edgeP<32, 64, 32, 32, 4, 12><<<dim3(XB, 4), 768, 0, stream>>>(
                xiBh, ea, cw1[1], cb1[1], w2t1, srcS, eord, msgP, TPB);
        }
        k_red<4><<<REDB, 256, 0, stream>>>(msgP);
        k_aggF<32, 64, 32><<<(NN * 8 + 255) / 256, 256, 0, stream>>>(
            msg, rowptr, xiB, croot[1], cbias[1], xiA, xiAh);

        // ---- layer 2: persistent-B, 8 k-slices (<=136 KB LDS), 12-wave blocks ----
        {
            const int XB = 32, TPB = (TILES + 31) / 32;   // 30
            k_edgeP<64, 64, 64, 16, 8, 12><<<dim3(XB, 8), 768, 0, stream>>>(
                xiAh, ea, cw1[2], cb1[2], w2t2, srcS, eord, msgP, TPB);
        }
        k_red<8><<<REDB, 256, 0, stream>>>(msgP);
        k_agg_poolF<<<(NN * 9 + 255) / 256, 256, 0, stream>>>(
            msg, rowptr, xiA, croot[2], cbias[2], x, n2s, xs_sum, cs);
    } else {
        k_edgeB<16, 32, 16><<<EB, 256, 0, stream>>>(x16h, ea, cw1[0], cb1[0], w2t0, srcS, eord, msg);
        k_aggF<16, 32, 24><<<(NN * 4 + 255) / 256, 256, 0, stream>>>(
            msg, rowptr, x, croot[0], cbias[0], xiB, xiBh);
        k_edgeB<32, 64, 32><<<EB, 256, 0, stream>>>(xiBh, ea, cw1[1], cb1[1], w2t1, srcS, eord, msg);
        k_aggF<32, 64, 32><<<(NN * 8 + 255) / 256, 256, 0, stream>>>(
            msg, rowptr, xiB, croot[1], cbias[1], xiA, xiAh);
        k_edgeB<64, 64, 64><<<EB, 256, 0, stream>>>(xiAh, ea, cw1[2], cb1[2], w2t2, srcS, eord, msg);
        k_agg_poolF<<<(NN * 9 + 255) / 256, 256, 0, stream>>>(
            msg, rowptr, xiA, croot[2], cbias[2], x, n2s, xs_sum, cs);
    }

    // ---- pooling + MLP ----
    k_pool_g<<<(NS * 72 + 255) / 256, 256, 0, stream>>>(xs_sum, cs, s2g, xg_sum, cg);
    k_fc<<<1, 128, 0, stream>>>(xg_sum, cg, fc1w, fc1b, fc2w, fc2b, fc3w, fc3b, (float*)d_out);
}

// Round 24
// 275.465 us; speedup vs baseline: 1.1894x; 1.1894x over previous
//
#include <hip/hip_runtime.h>
#include <hip/hip_bf16.h>
#include <cmath>

#define NN 20000   // nodes
#define NE 60000   // edges
#define NS 3000    // subgraphs
#define NG 128     // graphs
#define HIDN 128   // hidden dim of edge-attr MLP
#define SCB 79     // scan blocks = ceil(NN/256)
#define TILES 938  // ceil(NE/64)
#define SLST 3840000   // slice stride in f16 elems = NE*64

typedef float f32x16 __attribute__((ext_vector_type(16)));
typedef _Float16 f16x8 __attribute__((ext_vector_type(8)));

__device__ __forceinline__ float eluf(float v) { return v > 0.f ? v : expm1f(v); }

// async global->LDS, 16B per lane; lds ptr must be wave-uniform (HW writes base + lane*16)
__device__ __forceinline__ void gload_lds16(const void* g, void* l) {
    __builtin_amdgcn_global_load_lds(
        (const __attribute__((address_space(1))) unsigned int*)g,
        (__attribute__((address_space(3))) unsigned int*)l, 16, 0, 0);
}

__device__ __forceinline__ void vmwait0() {
    asm volatile("s_waitcnt vmcnt(0)" ::: "memory");
}
__device__ __forceinline__ void vmwait8() {
    asm volatile("s_waitcnt vmcnt(8)" ::: "memory");
}

// ================= one-time edge sort by dst (counting sort) =================
__global__ void k_hist(const int* __restrict__ dst, int* __restrict__ deg) {
    int e = blockIdx.x * 256 + threadIdx.x;
    if (e < NE) atomicAdd(&deg[dst[e]], 1);
}

__global__ void k_scan1(const int* __restrict__ deg, int* __restrict__ bsum) {
    __shared__ int s[256];
    const int t = threadIdx.x;
    int i = blockIdx.x * 256 + t;
    s[t] = (i < NN) ? deg[i] : 0;
    __syncthreads();
#pragma unroll
    for (int off = 128; off > 0; off >>= 1) {
        if (t < off) s[t] += s[t + off];
        __syncthreads();
    }
    if (t == 0) bsum[blockIdx.x] = s[0];
}

__global__ void k_scan2(const int* __restrict__ bsum, int* __restrict__ boff) {
    __shared__ int s[SCB];
    const int t = threadIdx.x;
    if (t < SCB) s[t] = bsum[t];
    __syncthreads();
    if (t == 0) {
        int acc = 0;
        for (int i = 0; i < SCB; ++i) { int v = s[i]; s[i] = acc; acc += v; }
    }
    __syncthreads();
    if (t < SCB) boff[t] = s[t];
}

__global__ void k_scan3(const int* __restrict__ deg, const int* __restrict__ boff,
                        int* __restrict__ rowptr) {
    __shared__ int s[256];
    const int t = threadIdx.x;
    int i = blockIdx.x * 256 + t;
    int v = (i < NN) ? deg[i] : 0;
    s[t] = v;
    __syncthreads();
#pragma unroll
    for (int off = 1; off < 256; off <<= 1) {
        int a = (t >= off) ? s[t - off] : 0;
        __syncthreads();
        s[t] += a;
        __syncthreads();
    }
    if (i < NN) rowptr[i + 1] = boff[blockIdx.x] + s[t];
    if (i == 0) rowptr[0] = 0;
}

__global__ void k_scatter(const int* __restrict__ src, const int* __restrict__ dst,
                          const int* __restrict__ rowptr, int* __restrict__ tmp,
                          int* __restrict__ eord, int* __restrict__ srcS) {
    int e = blockIdx.x * 256 + threadIdx.x;
    if (e >= NE) return;
    int d = dst[e];
    int pos = rowptr[d] + atomicAdd(&tmp[d], 1);
    eord[pos] = e;
    srcS[pos] = src[e];
}

// ---------------- combined prep: 3x w2t transposes + x16h, one dispatch ----------------
#define PRE_N0 66048    // 32*129*16   (layer 0)
#define PRE_N1 264192   // 64*129*32   (layer 1)
#define PRE_N2 528384   // 64*129*64   (layer 2)
#define PRE_N3 320000   // NN*16       (x16h)
#define PRE_TOT (PRE_N0 + PRE_N1 + PRE_N2 + PRE_N3)

__global__ void k_prep(const float* __restrict__ w20, const float* __restrict__ b20,
                       const float* __restrict__ w21, const float* __restrict__ b21,
                       const float* __restrict__ w22, const float* __restrict__ b22,
                       const float* __restrict__ x,
                       _Float16* __restrict__ w2t0, _Float16* __restrict__ w2t1,
                       _Float16* __restrict__ w2t2, _Float16* __restrict__ x16h) {
    int idx = blockIdx.x * 256 + threadIdx.x;
    if (idx < PRE_N0) {
        constexpr int KP = 129 * 16, KF = 128 * 16, MO = 32;
        int o = idx / KP, kg = idx % KP;
        float v = (kg < KF) ? w20[(size_t)kg * MO + o] : b20[(kg - KF) * MO + o];
        w2t0[idx] = (_Float16)v;
    } else if (idx < PRE_N0 + PRE_N1) {
        int i2 = idx - PRE_N0;
        constexpr int KP = 129 * 32, KF = 128 * 32, MO = 64;
        int o = i2 / KP, kg = i2 % KP;
        float v = (kg < KF) ? w21[(size_t)kg * MO + o] : b21[(kg - KF) * MO + o];
        w2t1[i2] = (_Float16)v;
    } else if (idx < PRE_N0 + PRE_N1 + PRE_N2) {
        int i2 = idx - PRE_N0 - PRE_N1;
        constexpr int KP = 129 * 64, KF = 128 * 64, MO = 64;
        int o = i2 / KP, kg = i2 % KP;
        float v = (kg < KF) ? w22[(size_t)kg * MO + o] : b22[(kg - KF) * MO + o];
        w2t2[i2] = (_Float16)v;
    } else if (idx < PRE_TOT) {
        int i2 = idx - PRE_N0 - PRE_N1 - PRE_N2;
        int n = i2 >> 4, i = i2 & 15;
        x16h[i2] = (_Float16)x[n * 24 + i];
    }
}

// ---------------- streaming MFMA edge kernel (fallback path only) ----------
template <int MI, int MO, int XS>
__global__ __launch_bounds__(256, 2) void k_edgeB(
    const _Float16* __restrict__ xi, const float* __restrict__ ea,
    const float* __restrict__ w1, const float* __restrict__ b1,
    const _Float16* __restrict__ w2t, const int* __restrict__ srcS,
    const int* __restrict__ eord, _Float16* __restrict__ msg) {
    constexpr int PH  = MI / 16;
    constexpr int KP  = 129 * MI;
    constexpr int NT  = MO / 32;
    constexpr int CH  = 16 / (PH * NT);
    constexpr int NCH = 64 / CH;
    static_assert(CH * PH * NT == 16, "ITEMS must be 16");

    __shared__ __align__(16) _Float16 sb[2][2][16 * 512];

    const int lane = threadIdx.x & 63;
    const int w    = threadIdx.x >> 6;
    const int mg   = w & 1;
    const int kh   = w >> 1;
    const int lo5  = lane & 31;
    const int hi   = lane >> 5;
    const int e0   = blockIdx.x * 128 + mg * 64;
    const int kb   = kh * 64;

    const int rc0 = min(e0 + lo5, NE - 1);
    const int rc1 = min(e0 + 32 + lo5, NE - 1);
    const int s0 = srcS[rc0];
    const int s1 = srcS[rc1];

    float ea0[5], ea1[5];
    {
        const int eo0 = eord[rc0], eo1 = eord[rc1];
#pragma unroll
        for (int d = 0; d < 5; ++d) {
            ea0[d] = ea[eo0 * 5 + d];
            ea1[d] = ea[eo1 * 5 + d];
        }
    }

    f16x8 xr0[PH], xr1[PH];
    {
        const _Float16* xb0 = xi + (size_t)s0 * XS + hi * 8;
        const _Float16* xb1 = xi + (size_t)s1 * XS + hi * 8;
#pragma unroll
        for (int p = 0; p < PH; ++p) {
            xr0[p] = *reinterpret_cast<const f16x8*>(xb0 + p * 16);
            xr1[p] = *reinterpret_cast<const f16x8*>(xb1 + p * 16);
        }
    }

    f32x16 acc[2][NT];
#pragma unroll
    for (int m = 0; m < 2; ++m)
#pragma unroll
        for (int n = 0; n < NT; ++n)
#pragma unroll
            for (int i = 0; i < 16; ++i) acc[m][n][i] = 0.f;

    auto stage = [&](int buf, int kc) {
#pragma unroll
        for (int jj = 0; jj < 8; ++jj) {
            const int j  = mg + jj * 2;
            const int n  = j % NT;
            const int kp = j / NT;
            const int p  = kp % PH;
            const int kk = kp / PH;
            gload_lds16(w2t + (size_t)(n * 32 + lo5) * KP
                            + (size_t)(kb + kc + kk) * MI + p * 16 + hi * 8,
                        &sb[kh][buf][j * 512]);
        }
    };

    auto calc_h = [&](int kc, _Float16* h0, _Float16* h1) {
#pragma unroll
        for (int kk = 0; kk < CH; ++kk) {
            const int k = kb + kc + kk;
            const float c0 = w1[0 * HIDN + k], c1 = w1[1 * HIDN + k],
                        c2 = w1[2 * HIDN + k], c3 = w1[3 * HIDN + k],
                        c4 = w1[4 * HIDN + k], bb = b1[k];
            float t0 = bb, t1 = bb;
            t0 = fmaf(ea0[0], c0, t0); t1 = fmaf(ea1[0], c0, t1);
            t0 = fmaf(ea0[1], c1, t0); t1 = fmaf(ea1[1], c1, t1);
            t0 = fmaf(ea0[2], c2, t0); t1 = fmaf(ea1[2], c2, t1);
            t0 = fmaf(ea0[3], c3, t0); t1 = fmaf(ea1[3], c3, t1);
            t0 = fmaf(ea0[4], c4, t0); t1 = fmaf(ea1[4], c4, t1);
            h0[kk] = (_Float16)fmaxf(t0, 0.f);
            h1[kk] = (_Float16)fmaxf(t1, 0.f);
        }
    };

    auto compute = [&](int buf, const _Float16* h0, const _Float16* h1) {
        const _Float16* sbc = &sb[kh][buf][0];
#pragma unroll
        for (int kk = 0; kk < CH; ++kk) {
            const _Float16 hv0 = h0[kk];
            const _Float16 hv1 = h1[kk];
            const f16x8 h80 = {hv0, hv0, hv0, hv0, hv0, hv0, hv0, hv0};
            const f16x8 h81 = {hv1, hv1, hv1, hv1, hv1, hv1, hv1, hv1};
#pragma unroll
            for (int p = 0; p < PH; ++p) {
                const f16x8 af0 = xr0[p] * h80;
                const f16x8 af1 = xr1[p] * h81;
#pragma unroll
                for (int n = 0; n < NT; ++n) {
                    const f16x8 bv = *reinterpret_cast<const f16x8*>(
                        &sbc[((kk * PH + p) * NT + n) * 512 + lane * 8]);
                    acc[0][n] = __builtin_amdgcn_mfma_f32_32x32x16_f16(af0, bv, acc[0][n], 0, 0, 0);
                    acc[1][n] = __builtin_amdgcn_mfma_f32_32x32x16_f16(af1, bv, acc[1][n], 0, 0, 0);
                }
            }
        }
    };

    _Float16 hA0[CH], hA1[CH], hB0[CH], hB1[CH];

    stage(0, 0);
    calc_h(0, hA0, hA1);

    for (int c = 0; c < NCH; c += 2) {
        stage(1, (c + 1) * CH);
        calc_h((c + 1) * CH, hB0, hB1);
        vmwait8();
        __builtin_amdgcn_sched_barrier(0);
        __builtin_amdgcn_s_barrier();
        __builtin_amdgcn_sched_barrier(0);
        compute(0, hA0, hA1);
        __builtin_amdgcn_sched_barrier(0);
        __builtin_amdgcn_s_barrier();

        const bool pf = (c + 2 < NCH);
        if (pf) {
            stage(0, (c + 2) * CH);
            calc_h((c + 2) * CH, hA0, hA1);
            vmwait8();
        } else {
            vmwait0();
        }
        __builtin_amdgcn_sched_barrier(0);
        __builtin_amdgcn_s_barrier();
        __builtin_amdgcn_sched_barrier(0);
        compute(1, hB0, hB1);
        __builtin_amdgcn_sched_barrier(0);
        __builtin_amdgcn_s_barrier();
    }

    if (kh == 1) {
#pragma unroll
        for (int p = 0; p < PH; ++p) {
#pragma unroll
            for (int n = 0; n < NT; ++n) {
                const f16x8 bv = *reinterpret_cast<const f16x8*>(
                    w2t + (size_t)(n * 32 + lo5) * KP + (size_t)128 * MI + p * 16 + hi * 8);
                acc[0][n] = __builtin_amdgcn_mfma_f32_32x32x16_f16(xr0[p], bv, acc[0][n], 0, 0, 0);
                acc[1][n] = __builtin_amdgcn_mfma_f32_32x32x16_f16(xr1[p], bv, acc[1][n], 0, 0, 0);
            }
        }
    }

    __syncthreads();
    float* red = reinterpret_cast<float*>(&sb[0][0][0]);
    if (kh == 1) {
#pragma unroll
        for (int m = 0; m < 2; ++m)
#pragma unroll
            for (int n = 0; n < NT; ++n) {
                float* d = red + (size_t)((mg * 2 + m) * NT + n) * 1024 + lane;
#pragma unroll
                for (int i = 0; i < 16; ++i) d[i * 64] = acc[m][n][i];
            }
    }
    __syncthreads();
    if (kh == 0) {
#pragma unroll
        for (int m = 0; m < 2; ++m)
#pragma unroll
            for (int n = 0; n < NT; ++n) {
                const float* s = red + (size_t)((mg * 2 + m) * NT + n) * 1024 + lane;
#pragma unroll
                for (int i = 0; i < 16; ++i) acc[m][n][i] += s[i * 64];
            }
#pragma unroll
        for (int m = 0; m < 2; ++m)
#pragma unroll
            for (int q = 0; q < 4; ++q)
#pragma unroll
                for (int a2 = 0; a2 < 4; ++a2) {
                    const int e = e0 + m * 32 + 4 * hi + 8 * q + a2;
                    if (e < NE) {
#pragma unroll
                        for (int n = 0; n < NT; ++n)
                            msg[(size_t)e * MO + n * 32 + lo5] =
                                (_Float16)acc[m][n][4 * q + a2];
                    }
                }
    }
}

// ---------------- persistent-B MFMA edge kernel (generalized) ----------------
// blockIdx.y = k-slice (NSL slices of KSL k, last has 129-(NSL-1)*KSL incl. b2-tail).
// B-slice loaded ONCE into LDS; WV waves free-run over 64-edge tiles, zero barriers.
// Slice sl writes partial msgP + sl*(NE*MO); partials summed by k_red (NSL>1).
template <int MI, int MO, int XS, int KSL, int NSL, int WV>
__global__ __launch_bounds__(WV * 64, WV / 4) void k_edgeP(
    const _Float16* __restrict__ xi, const float* __restrict__ ea,
    const float* __restrict__ w1, const float* __restrict__ b1,
    const _Float16* __restrict__ w2t, const int* __restrict__ srcS,
    const int* __restrict__ eord, _Float16* __restrict__ msgP, int tilesPerBlock) {
    constexpr int PH = MI / 16;
    constexpr int KP = 129 * MI;
    constexpr int NT = MO / 32;
    constexpr int LASTK = 129 - (NSL - 1) * KSL;
    constexpr int MAXITEMS = LASTK * PH * NT;   // last slice is largest

    __shared__ __align__(16) _Float16 sb[MAXITEMS * 512];

    const int t    = threadIdx.x;
    const int lane = t & 63;
    const int w    = t >> 6;
    const int lo5  = lane & 31;
    const int hi   = lane >> 5;

    const int sl    = blockIdx.y;
    const int k0    = sl * KSL;
    const int kspan = (sl == NSL - 1) ? LASTK : KSL;
    const int items = kspan * PH * NT;

    // one-time B-slice load
    for (int j = w; j < items; j += WV) {
        const int kk  = j / (PH * NT);
        const int rem = j % (PH * NT);
        const int p   = rem / NT;
        const int n   = rem % NT;
        gload_lds16(w2t + (size_t)(n * 32 + lo5) * KP
                        + (size_t)(k0 + kk) * MI + p * 16 + hi * 8,
                    &sb[j * 512]);
    }
    vmwait0();
    __syncthreads();

    _Float16* msgS = msgP + (size_t)sl * ((size_t)NE * MO);
    const int tile0 = blockIdx.x * tilesPerBlock;
    const int tile1 = min(tile0 + tilesPerBlock, TILES);

    for (int tile = tile0 + w; tile < tile1; tile += WV) {
        const int e0  = tile * 64;
        const int rc0 = min(e0 + lo5, NE - 1);
        const int rc1 = min(e0 + 32 + lo5, NE - 1);
        const int s0 = srcS[rc0];
        const int s1 = srcS[rc1];

        float ea0[5], ea1[5];
        {
            const int eo0 = eord[rc0], eo1 = eord[rc1];
#pragma unroll
            for (int d = 0; d < 5; ++d) {
                ea0[d] = ea[eo0 * 5 + d];
                ea1[d] = ea[eo1 * 5 + d];
            }
        }

        f16x8 xr0[PH], xr1[PH];
        {
            const _Float16* xb0 = xi + (size_t)s0 * XS + hi * 8;
            const _Float16* xb1 = xi + (size_t)s1 * XS + hi * 8;
#pragma unroll
            for (int p = 0; p < PH; ++p) {
                xr0[p] = *reinterpret_cast<const f16x8*>(xb0 + p * 16);
                xr1[p] = *reinterpret_cast<const f16x8*>(xb1 + p * 16);
            }
        }

        f32x16 acc[2][NT];
#pragma unroll
        for (int m = 0; m < 2; ++m)
#pragma unroll
            for (int n = 0; n < NT; ++n)
#pragma unroll
                for (int i = 0; i < 16; ++i) acc[m][n][i] = 0.f;

        for (int kk2 = 0; kk2 < kspan; ++kk2) {
            const int k = k0 + kk2;
            _Float16 hv0, hv1;
            if (k < 128) {
                const float c0 = w1[0 * HIDN + k], c1 = w1[1 * HIDN + k],
                            c2 = w1[2 * HIDN + k], c3 = w1[3 * HIDN + k],
                            c4 = w1[4 * HIDN + k], bb = b1[k];
                float t0 = bb, t1 = bb;
                t0 = fmaf(ea0[0], c0, t0); t1 = fmaf(ea1[0], c0, t1);
                t0 = fmaf(ea0[1], c1, t0); t1 = fmaf(ea1[1], c1, t1);
                t0 = fmaf(ea0[2], c2, t0); t1 = fmaf(ea1[2], c2, t1);
                t0 = fmaf(ea0[3], c3, t0); t1 = fmaf(ea1[3], c3, t1);
                t0 = fmaf(ea0[4], c4, t0); t1 = fmaf(ea1[4], c4, t1);
                hv0 = (_Float16)fmaxf(t0, 0.f);
                hv1 = (_Float16)fmaxf(t1, 0.f);
            } else {
                hv0 = (_Float16)1.0f;
                hv1 = (_Float16)1.0f;
            }
            const f16x8 h80 = {hv0, hv0, hv0, hv0, hv0, hv0, hv0, hv0};
            const f16x8 h81 = {hv1, hv1, hv1, hv1, hv1, hv1, hv1, hv1};
#pragma unroll
            for (int p = 0; p < PH; ++p) {
                const f16x8 af0 = xr0[p] * h80;
                const f16x8 af1 = xr1[p] * h81;
#pragma unroll
                for (int n = 0; n < NT; ++n) {
                    const f16x8 bv = *reinterpret_cast<const f16x8*>(
                        &sb[((kk2 * PH + p) * NT + n) * 512 + lane * 8]);
                    acc[0][n] = __builtin_amdgcn_mfma_f32_32x32x16_f16(af0, bv, acc[0][n], 0, 0, 0);
                    acc[1][n] = __builtin_amdgcn_mfma_f32_32x32x16_f16(af1, bv, acc[1][n], 0, 0, 0);
                }
            }
        }

        // store partial: C layout col = lane&31, row = (reg&3) + 8*(reg>>2) + 4*(lane>>5)
#pragma unroll
        for (int m = 0; m < 2; ++m)
#pragma unroll
            for (int q = 0; q < 4; ++q)
#pragma unroll
                for (int a2 = 0; a2 < 4; ++a2) {
                    const int e = e0 + m * 32 + 4 * hi + 8 * q + a2;
                    if (e < NE) {
#pragma unroll
                        for (int n = 0; n < NT; ++n)
                            msgS[(size_t)e * MO + n * 32 + lo5] =
                                (_Float16)acc[m][n][4 * q + a2];
                    }
                }
    }
}

// ---------------- slice reduction: msg[idx] = sum over NSL partials (coalesced f16x8) ------
template <int NSL>
__global__ void k_red(_Float16* __restrict__ msgP) {
    int idx = blockIdx.x * 256 + threadIdx.x;   // in f16x8 units; total = NE*64/8 = 480000
    if (idx >= NE * 8) return;                  // NE*64/8
    float a[8] = {0, 0, 0, 0, 0, 0, 0, 0};
#pragma unroll
    for (int sl = 0; sl < NSL; ++sl) {
        const f16x8 v = *reinterpret_cast<const f16x8*>(msgP + (size_t)sl * SLST + (size_t)idx * 8);
#pragma unroll
        for (int i = 0; i < 8; ++i) a[i] += (float)v[i];
    }
    f16x8 r;
#pragma unroll
    for (int i = 0; i < 8; ++i) r[i] = (_Float16)a[i];
    *reinterpret_cast<f16x8*>(msgP + (size_t)idx * 8) = r;
}

// ---------------- agg (layers 0,1): out = elu(bias + xi@root + CSR-sum msg); f32+f16 out ----
template <int MI, int MO, int XS>
__global__ void k_agg(const _Float16* __restrict__ msg, const int* __restrict__ rowptr,
                      const float* __restrict__ xi, const float* __restrict__ root,
                      const float* __restrict__ bias, float* __restrict__ out,
                      _Float16* __restrict__ outh) {
    int idx = blockIdx.x * 256 + threadIdx.x;
    if (idx >= NN * MO) return;
    int n = idx / MO, o = idx % MO;
    float s = bias[o];
#pragma unroll
    for (int i = 0; i < MI; ++i) s = fmaf(xi[(size_t)n * XS + i], root[i * MO + o], s);
    const int j0 = rowptr[n], j1 = rowptr[n + 1];
    for (int j = j0; j < j1; ++j) s += (float)msg[(size_t)j * MO + o];
    float r = eluf(s);
    out[idx] = r;
    outh[idx] = (_Float16)r;
}

// ---------------- layer-2 agg fused with node->subgraph pooling (single msg) ----------------
__global__ void k_agg_pool(const _Float16* __restrict__ msg, const int* __restrict__ rowptr,
                           const float* __restrict__ xi, const float* __restrict__ root,
                           const float* __restrict__ bias, const float* __restrict__ x,
                           const int* __restrict__ n2s, float* __restrict__ xs_sum,
                           float* __restrict__ cs) {
    int idx = blockIdx.x * 256 + threadIdx.x;
    if (idx >= NN * 72) return;
    int n = idx / 72, o = idx % 72;
    float r;
    if (o < 64) {
        float s = bias[o];
#pragma unroll
        for (int i = 0; i < 64; ++i) s = fmaf(xi[(size_t)n * 64 + i], root[i * 64 + o], s);
        const int j0 = rowptr[n], j1 = rowptr[n + 1];
        for (int j = j0; j < j1; ++j) s += (float)msg[(size_t)j * 64 + o];
        r = eluf(s);
    } else {
        r = x[n * 24 + 16 + (o - 64)];
    }
    const int sg = n2s[n];
    atomicAdd(&xs_sum[sg * 72 + o], r);
    if (o == 0) atomicAdd(&cs[sg], 1.f);
}

// ---------------- pool subgraphs -> graphs (mean of means) ----------------
__global__ void k_pool_g(const float* __restrict__ xs_sum, const float* __restrict__ cs,
                         const int* __restrict__ s2g, float* __restrict__ xg_sum,
                         float* __restrict__ cg) {
    int idx = blockIdx.x * 256 + threadIdx.x;
    if (idx >= NS * 72) return;
    int s = idx / 72, j = idx % 72;
    float v = xs_sum[s * 72 + j] / fmaxf(cs[s], 1.f);
    int g = s2g[s];
    atomicAdd(&xg_sum[g * 72 + j], v);
    if (j == 0) atomicAdd(&cg[g], 1.f);
}

// ---------------- final MLP: 72 -> 36 -> 18 -> 1 ----------------
__global__ void k_fc(const float* __restrict__ xg_sum, const float* __restrict__ cg,
                     const float* __restrict__ w1, const float* __restrict__ b1,
                     const float* __restrict__ w2, const float* __restrict__ b2,
                     const float* __restrict__ w3, const float* __restrict__ b3,
                     float* __restrict__ out) {
    int g = threadIdx.x;
    if (g >= NG) return;
    float inv = 1.f / fmaxf(cg[g], 1.f);
    float v[72];
#pragma unroll
    for (int j = 0; j < 72; ++j) v[j] = xg_sum[g * 72 + j] * inv;
    float h1[36];
#pragma unroll
    for (int o = 0; o < 36; ++o) {
        float s = b1[o];
#pragma unroll
        for (int i = 0; i < 72; ++i) s = fmaf(v[i], w1[i * 36 + o], s);
        h1[o] = eluf(s);
    }
    float h2[18];
#pragma unroll
    for (int o = 0; o < 18; ++o) {
        float s = b2[o];
#pragma unroll
        for (int i = 0; i < 36; ++i) s = fmaf(h1[i], w2[i * 18 + o], s);
        h2[o] = eluf(s);
    }
    float s = b3[0];
#pragma unroll
    for (int i = 0; i < 18; ++i) s = fmaf(h2[i], w3[i], s);
    out[g] = s;
}

// ---------------- launcher ----------------
extern "C" void kernel_launch(void* const* d_in, const int* in_sizes, int n_in,
                              void* d_out, int out_size, void* d_ws, size_t ws_size,
                              hipStream_t stream) {
    const float* x   = (const float*)d_in[0];
    const int*   ei  = (const int*)d_in[1];
    const float* ea  = (const float*)d_in[2];
    const int*   n2s = (const int*)d_in[3];
    const int*   s2g = (const int*)d_in[4];
    const int* src = ei;
    const int* dst = ei + NE;

    const float* cw1[3]   = {(const float*)d_in[5],  (const float*)d_in[11], (const float*)d_in[17]};
    const float* cb1[3]   = {(const float*)d_in[6],  (const float*)d_in[12], (const float*)d_in[18]};
    const float* cw2[3]   = {(const float*)d_in[7],  (const float*)d_in[13], (const float*)d_in[19]};
    const float* cb2[3]   = {(const float*)d_in[8],  (const float*)d_in[14], (const float*)d_in[20]};
    const float* croot[3] = {(const float*)d_in[9],  (const float*)d_in[15], (const float*)d_in[21]};
    const float* cbias[3] = {(const float*)d_in[10], (const float*)d_in[16], (const float*)d_in[22]};
    const float* fc1w = (const float*)d_in[23];
    const float* fc1b = (const float*)d_in[24];
    const float* fc2w = (const float*)d_in[25];
    const float* fc2b = (const float*)d_in[26];
    const float* fc3w = (const float*)d_in[27];
    const float* fc3b = (const float*)d_in[28];

    // ---- workspace layout (bytes, 16-aligned) ----
    char* W = (char*)d_ws;
    float*    xiA   = (float*)(W);                    // NN*64*4    =  5,120,000
    float*    xiB   = (float*)(W + 5120000);          // NN*64*4    =  5,120,000
    _Float16* xiAh  = (_Float16*)(W + 10240000);      // NN*64*2    =  2,560,000
    _Float16* xiBh  = (_Float16*)(W + 12800000);      // NN*64*2    =  2,560,000
    _Float16* x16h  = (_Float16*)(W + 15360000);      // NN*16*2    =    640,000
    // zero region (single memset): xs_sum | cs | xg_sum | cg | deg | tmp
    float*    xs_sum= (float*)(W + 16000000);         // NS*72*4    =    864,000
    float*    cs    = (float*)(W + 16864000);         // NS*4       =     12,000
    float*    xg_sum= (float*)(W + 16876000);         // NG*72*4    =     36,864
    float*    cg    = (float*)(W + 16912864);         // NG*4       =        512
    int*      deg   = (int*)(W + 16913376);           // NN*4       =     80,000
    int*      tmp   = (int*)(W + 16993376);           // NN*4       =     80,000
    _Float16* w2t0  = (_Float16*)(W + 17073376);      // 32*2064*2  =    132,096
    _Float16* w2t1  = (_Float16*)(W + 17205472);      // 64*4128*2  =    528,384
    _Float16* w2t2  = (_Float16*)(W + 17733856);      // 64*8256*2  =  1,056,768
    int*      rowptr= (int*)(W + 18790624);           // (NN+1)*4   ->    80,016
    int*      eord  = (int*)(W + 18870640);           // NE*4       =    240,000
    int*      srcS  = (int*)(W + 19110640);           // NE*4       =    240,000
    int*      bsum  = (int*)(W + 19350640);           // SCB*4
    int*      boff  = (int*)(W + 19350960);           // SCB*4
    _Float16* msgP  = (_Float16*)(W + 19351296);      // up to 8 x NE*64*2 = 61,440,000
    const size_t NEED_P = 19351296ull + 8ull * 7680000ull;   // 80,791,296
    const bool useP = (ws_size >= NEED_P);
    _Float16* msg = msgP;   // slice 0

    // single memset: pooling accumulators + sort counters (contiguous)
    hipMemsetAsync(xs_sum, 0, 1073376, stream);

    // ---- one-time edge sort by dst (hierarchical scan) ----
    k_hist<<<(NE + 255) / 256, 256, 0, stream>>>(dst, deg);
    k_scan1<<<SCB, 256, 0, stream>>>(deg, bsum);
    k_scan2<<<1, 128, 0, stream>>>(bsum, boff);
    k_scan3<<<SCB, 256, 0, stream>>>(deg, boff, rowptr);
    k_scatter<<<(NE + 255) / 256, 256, 0, stream>>>(src, dst, rowptr, tmp, eord, srcS);

    // combined prep: w2t x3 + x16h in one dispatch
    k_prep<<<(PRE_TOT + 255) / 256, 256, 0, stream>>>(
        cw2[0], cb2[0], cw2[1], cb2[1], cw2[2], cb2[2], x, w2t0, w2t1, w2t2, x16h);

    const int EB = (NE + 127) / 128;   // 469 blocks of 4 waves (fallback)
    const int REDB = (NE * 8 + 255) / 256;  // 480000/256 = 1875

    if (useP) {
        // ---- layer 0: persistent-B, single slice (129 KB LDS), 8-wave blocks ----
        {
            const int XB = 118, TPB = 8;   // 118*8 = 944 >= 938 tiles
            k_edgeP<16, 32, 16, 129, 1, 8><<<dim3(XB, 1), 512, 0, stream>>>(
                x16h, ea, cw1[0], cb1[0], w2t0, srcS, eord, msg, TPB);
        }
        k_agg<16, 32, 24><<<(NN * 32 + 255) / 256, 256, 0, stream>>>(msg, rowptr, x, croot[0], cbias[0], xiB, xiBh);

        // ---- layer 1: persistent-B, 4 k-slices (<=132 KB LDS), 12-wave blocks ----
        {
            const int XB = 64, TPB = (TILES + 63) / 64;   // 15
            k_edgeP<32, 64, 32, 32, 4, 12><<<dim3(XB, 4), 768, 0, stream>>>(
                xiBh, ea, cw1[1], cb1[1], w2t1, srcS, eord, msgP, TPB);
        }
        k_red<4><<<REDB, 256, 0, stream>>>(msgP);
        k_agg<32, 64, 32><<<(NN * 64 + 255) / 256, 256, 0, stream>>>(msg, rowptr, xiB, croot[1], cbias[1], xiA, xiAh);

        // ---- layer 2: persistent-B, 8 k-slices (<=136 KB LDS), 12-wave blocks ----
        {
            const int XB = 32, TPB = (TILES + 31) / 32;   // 30
            k_edgeP<64, 64, 64, 16, 8, 12><<<dim3(XB, 8), 768, 0, stream>>>(
                xiAh, ea, cw1[2], cb1[2], w2t2, srcS, eord, msgP, TPB);
        }
        k_red<8><<<REDB, 256, 0, stream>>>(msgP);
        k_agg_pool<<<(NN * 72 + 255) / 256, 256, 0, stream>>>(
            msg, rowptr, xiA, croot[2], cbias[2], x, n2s, xs_sum, cs);
    } else {
        k_edgeB<16, 32, 16><<<EB, 256, 0, stream>>>(x16h, ea, cw1[0], cb1[0], w2t0, srcS, eord, msg);
        k_agg<16, 32, 24><<<(NN * 32 + 255) / 256, 256, 0, stream>>>(msg, rowptr, x, croot[0], cbias[0], xiB, xiBh);
        k_edgeB<32, 64, 32><<<EB, 256, 0, stream>>>(xiBh, ea, cw1[1], cb1[1], w2t1, srcS, eord, msg);
        k_agg<32, 64, 32><<<(NN * 64 + 255) / 256, 256, 0, stream>>>(msg, rowptr, xiB, croot[1], cbias[1], xiA, xiAh);
        k_edgeB<64, 64, 64><<<EB, 256, 0, stream>>>(xiAh, ea, cw1[2], cb1[2], w2t2, srcS, eord, msg);
        k_agg_pool<<<(NN * 72 + 255) / 256, 256, 0, stream>>>(
            msg, rowptr, xiA, croot[2], cbias[2], x, n2s, xs_sum, cs);
    }

    // ---- pooling + MLP ----
    k_pool_g<<<(NS * 72 + 255) / 256, 256, 0, stream>>>(xs_sum, cs, s2g, xg_sum, cg);
    k_fc<<<1, 128, 0, stream>>>(xg_sum, cg, fc1w, fc1b, fc2w, fc2b, fc3w, fc3b, (float*)d_out);
}